// Round 2
// baseline (4359.351 us; speedup 1.0000x reference)
//
#include <hip/hip_runtime.h>
#include <hip/hip_bf16.h>
#include <cstring>

typedef __attribute__((ext_vector_type(4))) float floatx4;
typedef unsigned int u32;
typedef unsigned short u16;

#define DEV static __device__ __forceinline__
DEV float sigf(float x){ return 1.f / (1.f + expf(-x)); }

// Sizes: B=64 L=128 E=300 H=256 4H=1024 NE=34 NA=36, M = B*L = 8192.
// ROUND 6: round 5 still spilled -- VGPR_Count=64 (not 128): compiler derives
// the VGPR budget from LDS-limited occupancy (55KB -> 2 WGs/CU -> 8 waves/SIMD
// -> 64 VGPRs), and w0[64] went to scratch (FETCH 4.4GB == 64*4*1024*128*128).
// Fix: LDS weight slab grown to 32 k-slices (128KB, total 134KB) -> 1 WG/CU ->
// 4 waves/SIMD -> 128-VGPR default budget (the heuristic that verifiably gave
// 128 before). k split: k<64 regs, [64,96) LDS, [96,256) streamed from L2
// (160 f32 = 640B/row, 16B-aligned).

// ---------------------------------------------------------------------------
// k_pack_whh: w_hh f32 [2][1024][256] -> wTk[k][dir*1024+g] (k<96, k-major)
//                                      + wS[(dir*1024+g)][160] (k in [96,256), g-major)
__global__ __launch_bounds__(256) void k_pack_whh(const float* __restrict__ whf,
                                                  const float* __restrict__ whb,
                                                  float* __restrict__ wTk,
                                                  float* __restrict__ wS)
{
  int i = blockIdx.x * 256 + threadIdx.x;            // 2*1024*256 = 524288
  if (i >= 524288) return;
  int dir = i >> 18, rem = i & 262143, g = rem >> 8, k = rem & 255;
  const float v = (dir ? whb : whf)[g*256 + k];
  if (k < 96) wTk[(size_t)k*2048 + dir*1024 + g] = v;
  else        wS[(size_t)(dir*1024 + g)*160 + (k - 96)] = v;
}

// k_pack_wcat: WcatT[k][128]: col<34 event_w[col][k]; 34..69 arg_w[col-34][512+k];
//              70..105 arg_w[col-70][k]; 106..127 zero.
__global__ __launch_bounds__(256) void k_pack_wcat(const float* __restrict__ evw,
                                                   const float* __restrict__ argw,
                                                   float* __restrict__ WcatT)
{
  int i = blockIdx.x * 256 + threadIdx.x;            // 512*128 = 65536
  if (i >= 65536) return;
  int k = i >> 7, col = i & 127;
  float v = 0.f;
  if (col < 34)        v = evw[(size_t)col*512 + k];
  else if (col < 70)   v = argw[(size_t)(col-34)*1092 + 512 + k];
  else if (col < 106)  v = argw[(size_t)(col-70)*1092 + k];
  WcatT[(size_t)k*128 + col] = v;
}

// ---------------------------------------------------------------------------
// k_xg: xg[dir][m][g] = sum_e emb[ids[m]][e]*w_ih[dir][g][e] + b[dir][g]. Pure f32.
// 64x64 tile, BK=16, 256 thr, 4x4 micro.
__global__ __launch_bounds__(256) void k_xg(const int* __restrict__ ids,
    const float* __restrict__ emb,
    const float* __restrict__ wihf, const float* __restrict__ wihb,
    const float* __restrict__ bf_, const float* __restrict__ bb_,
    float* __restrict__ xg)
{
  const int dir = blockIdx.z;
  const float* W    = dir ? wihb : wihf;
  const float* bias = dir ? bb_  : bf_;
  const int n0 = blockIdx.x * 64, m0 = blockIdx.y * 64;
  __shared__ float As[16][64];
  __shared__ float Bs[16][64];
  const int tid = threadIdx.x;
  const int row = tid & 63, kk = (tid >> 6) * 4;
  const int tx = tid & 15, ty = tid >> 4;
  const size_t abase = (size_t)ids[m0 + row] * 300;
  const size_t bbase = (size_t)(n0 + row) * 300;
  float acc[4][4] = {};

  for (int k0 = 0; k0 < 300; k0 += 16) {
    __syncthreads();
    {
      const int gk = k0 + kk;
      floatx4 va = {0,0,0,0}, vb = {0,0,0,0};
      if (gk + 3 < 300) {
        va = *(const floatx4*)(emb + abase + gk);
        vb = *(const floatx4*)(W   + bbase + gk);
      } else {
        #pragma unroll
        for (int j = 0; j < 4; j++) if (gk + j < 300) {
          va[j] = emb[abase + gk + j];
          vb[j] = W[bbase + gk + j];
        }
      }
      #pragma unroll
      for (int j = 0; j < 4; j++){ As[kk+j][row] = va[j]; Bs[kk+j][row] = vb[j]; }
    }
    __syncthreads();
    #pragma unroll
    for (int k = 0; k < 16; k++){
      const floatx4 av = *(const floatx4*)&As[k][ty*4];
      const floatx4 bv = *(const floatx4*)&Bs[k][tx*4];
      #pragma unroll
      for (int i = 0; i < 4; i++)
        #pragma unroll
        for (int j = 0; j < 4; j++) acc[i][j] += av[i] * bv[j];
    }
  }
  const floatx4 bv = *(const floatx4*)(bias + n0 + tx*4);
  #pragma unroll
  for (int i = 0; i < 4; i++){
    const int m = m0 + ty*4 + i;
    floatx4 o;
    #pragma unroll
    for (int j = 0; j < 4; j++) o[j] = acc[i][j] + bv[j];
    *(floatx4*)&xg[(size_t)dir*8388608 + (size_t)m*1024 + n0 + tx*4] = o;
  }
}

// ---------------------------------------------------------------------------
// k_lstm: 128 WGs = (dir,b), 1024 thr, 1 gate/thread. Exact f32.
// LDS 134KB -> 1 WG/CU -> 4 waves/SIMD -> 128-VGPR budget; w0[64] stays in regs.
// k<64 regs; k in [64,96) LDS wl (stride-1 across lanes, conflict-free);
// k in [96,256) streamed as 16B-aligned 640B rows from L2 (wS 1.28MB resident).
__global__ __attribute__((amdgpu_flat_work_group_size(1024,1024), amdgpu_waves_per_eu(4,4)))
void k_lstm(const float* __restrict__ xg,
    const float* __restrict__ wTk, const float* __restrict__ wS,
    float* __restrict__ hs)
{
  const int wg = blockIdx.x;
  const int dir = wg >> 6, b = wg & 63, dirbase = dir * 1024;
  const int t = threadIdx.x;
  __shared__ float wl[32 * 1024];                 // k in [64,96), 128KB
  __shared__ float __align__(16) hl[2][256];
  __shared__ float gates[1024];

  float w0[64];
  #pragma unroll
  for (int i = 0; i < 64; i++)
    w0[i] = wTk[(size_t)i*2048 + dirbase + t];
  for (int f = t; f < 32768; f += 1024)
    wl[f] = wTk[(size_t)(64 + (f >> 10))*2048 + dirbase + (f & 1023)];

  const float* s0 = wS + (size_t)(dirbase + t) * 160;   // 640B rows, 16B aligned

  float c = 0.f;
  if (t < 256) hl[0][t] = 0.f;
  __syncthreads();

  const float* xgbase = xg + (size_t)dir*8388608 + (size_t)b*131072;
  float* hsbase = hs + (size_t)b*65536 + dir*256;

  for (int s = 0; s < 128; s++){
    const int tstep = dir ? (127 - s) : s;
    const float x0 = __builtin_nontemporal_load(xgbase + (size_t)tstep*1024 + t);
    const float* hcur = hl[s & 1];
    float a0 = 0.f;

    #pragma unroll
    for (int q = 0; q < 16; q++){                 // k in [0,64) from regs
      const floatx4 hv = *(const floatx4*)&hcur[q*4];
      #pragma unroll
      for (int e = 0; e < 4; e++) a0 += w0[q*4+e] * hv[e];
    }
    #pragma unroll
    for (int k = 0; k < 32; k++)                  // k in [64,96) from LDS
      a0 += wl[k*1024 + t] * hcur[64 + k];
    #pragma unroll
    for (int q = 0; q < 40; q++){                 // k in [96,256) from L2
      const floatx4 wv = *(const floatx4*)(s0 + q*4);
      const floatx4 hv = *(const floatx4*)&hcur[96 + q*4];
      #pragma unroll
      for (int e = 0; e < 4; e++) a0 += wv[e] * hv[e];
    }

    gates[t] = x0 + a0;
    __syncthreads();
    if (t < 256){
      const float gi = gates[t], gf = gates[256 + t], gg = gates[512 + t], go = gates[768 + t];
      c = sigf(gf)*c + sigf(gi)*tanhf(gg);
      const float h = sigf(go)*tanhf(c);
      hl[(s + 1) & 1][t] = h;
      hsbase[(size_t)tstep*512 + t] = h;
    }
    __syncthreads();
  }
}

// ---------------------------------------------------------------------------
// k_hmm: P[8192][128] = hs[8192][512] @ WcatT (f32, 64x64 tile, BK=16)
__global__ __launch_bounds__(256) void k_hmm(const float* __restrict__ hs,
    const float* __restrict__ WcatT, float* __restrict__ P)
{
  const int n0 = blockIdx.x * 64, m0 = blockIdx.y * 64;
  __shared__ float As[16][64];
  __shared__ float Bs[16][64];
  const int tid = threadIdx.x;
  const int row = tid & 63, kk = (tid >> 6) * 4;
  const int tx = tid & 15, ty = tid >> 4;
  float acc[4][4] = {};

  for (int k0 = 0; k0 < 512; k0 += 16) {
    __syncthreads();
    {
      const floatx4 va = *(const floatx4*)(hs + (size_t)(m0+row)*512 + k0 + kk);
      #pragma unroll
      for (int j = 0; j < 4; j++){
        As[kk+j][row] = va[j];
        Bs[kk+j][row] = WcatT[(size_t)(k0+kk+j)*128 + n0 + row];
      }
    }
    __syncthreads();
    #pragma unroll
    for (int k = 0; k < 16; k++){
      const floatx4 av = *(const floatx4*)&As[k][ty*4];
      const floatx4 bv = *(const floatx4*)&Bs[k][tx*4];
      #pragma unroll
      for (int i = 0; i < 4; i++)
        #pragma unroll
        for (int j = 0; j < 4; j++) acc[i][j] += av[i] * bv[j];
    }
  }
  #pragma unroll
  for (int i = 0; i < 4; i++){
    floatx4 o;
    #pragma unroll
    for (int j = 0; j < 4; j++) o[j] = acc[i][j];
    *(floatx4*)&P[(size_t)(m0 + ty*4 + i)*128 + n0 + tx*4] = o;
  }
}

// ---------------------------------------------------------------------------
// k_post: per row m: ev logits (+event_b) -> f32 out + argmax -> evact;
//         trig = P[34..69]; base = P[70..105] + arg_b.
__global__ __launch_bounds__(256) void k_post(const float* __restrict__ P,
    const float* __restrict__ evb, const float* __restrict__ argb,
    float* __restrict__ ev_out, float* __restrict__ trig,
    float* __restrict__ base, int* __restrict__ evact)
{
  const int m = blockIdx.x * 256 + threadIdx.x;
  const float* row = P + (size_t)m*128;
  float bestv = row[0] + evb[0]; int besti = 0;
  ev_out[(size_t)m*34] = bestv;
  for (int n = 1; n < 34; n++){
    const float v = row[n] + evb[n];
    ev_out[(size_t)m*34 + n] = v;
    if (v > bestv){ bestv = v; besti = n; }       // strict >: first-max tie rule
  }
  evact[m] = besti;
  for (int n = 0; n < 36; n++) trig[(size_t)m*36 + n] = row[34 + n];
  for (int n = 0; n < 36; n++) base[(size_t)m*36 + n] = row[70 + n] + argb[n];
}

// ---------------------------------------------------------------------------
// k_dec: 8192 independent (b,j) cells, 2 threads/cell (18 logits each).
// contrib[] updated incrementally when a g-bit flips 0->1.
__global__ __launch_bounds__(128) void k_dec(const float* __restrict__ trig,
    const float* __restrict__ base, const int* __restrict__ evact,
    const float* __restrict__ arg_w, float* __restrict__ out1)
{
  const int bb = blockIdx.x >> 1, jh = blockIdx.x & 1;
  const int tid = threadIdx.x;
  const int j = jh*64 + (tid >> 1), p = tid & 1;
  __shared__ float trig_l[128*36];
  __shared__ float Wg_l[35*36];    // [k][a], arg_w cols 1024+k
  __shared__ float Wtg_l[33*36];   // [k][a], arg_w cols 1059+k
  __shared__ int evact_l[128];

  for (int f = tid; f < 128*36; f += 128) trig_l[f] = trig[(size_t)bb*4608 + f];
  for (int f = tid; f < 35*36; f += 128){ int k = f/36, a = f - k*36; Wg_l[f]  = arg_w[(size_t)a*1092 + 1024 + k]; }
  for (int f = tid; f < 33*36; f += 128){ int k = f/36, a = f - k*36; Wtg_l[f] = arg_w[(size_t)a*1092 + 1059 + k]; }
  evact_l[tid] = evact[bb*128 + tid];

  float basev[18], contrib[18];
  #pragma unroll
  for (int x = 0; x < 18; x++){
    basev[x] = base[((size_t)bb*128 + j)*36 + p*18 + x];
    contrib[x] = 0.f;
  }
  unsigned long long garg = 0ull, gtrg = 0ull;
  __syncthreads();

  float* outb = out1 + (size_t)bb*589824 + (size_t)j*36;   // + i*4608 + p*18

  for (int i = 0; i < 128; i++){
    const float* tr = &trig_l[i*36 + p*18];
    float l[18];
    #pragma unroll
    for (int x = 0; x < 18; x++) l[x] = basev[x] + contrib[x] + tr[x];
    float mv = l[0]; int mi = p*18;
    #pragma unroll
    for (int x = 1; x < 18; x++){ if (l[x] > mv){ mv = l[x]; mi = p*18 + x; } }
    const float ov = __shfl_xor(mv, 1);
    const int   oi = __shfl_xor(mi, 1);
    const float v0 = p ? ov : mv, v1 = p ? mv : ov;
    const int   i0 = p ? oi : mi, i1 = p ? mi : oi;
    const int gidx = (v1 > v0) ? i1 : i0;          // first-max across both halves

    float* po = outb + (size_t)i*4608 + p*18;
    #pragma unroll
    for (int x = 0; x < 18; x++) po[x] = l[x];

    const int ev = evact_l[i];
    if (ev > 0 && gidx > 0){
      const int k1 = gidx - 1;
      const unsigned long long bit1 = 1ull << k1;
      if (!(garg & bit1)){
        garg |= bit1;
        const float* wc = &Wg_l[k1*36 + p*18];
        #pragma unroll
        for (int x = 0; x < 18; x++) contrib[x] += wc[x];
      }
      const int k2 = ev - 1;
      const unsigned long long bit2 = 1ull << k2;
      if (!(gtrg & bit2)){
        gtrg |= bit2;
        const float* wc = &Wtg_l[k2*36 + p*18];
        #pragma unroll
        for (int x = 0; x < 18; x++) contrib[x] += wc[x];
      }
    }
  }
}

// ---------------------------------------------------------------------------
extern "C" void kernel_launch(void* const* d_in, const int* in_sizes, int n_in,
                              void* d_out, int out_size, void* d_ws, size_t ws_size,
                              hipStream_t stream)
{
  const int*   ids  = (const int*)d_in[0];
  const float* emb  = (const float*)d_in[1];
  const float* wihf = (const float*)d_in[2];
  const float* whhf = (const float*)d_in[3];
  const float* bf_  = (const float*)d_in[4];
  const float* wihb = (const float*)d_in[5];
  const float* whhb = (const float*)d_in[6];
  const float* bb_  = (const float*)d_in[7];
  const float* evw  = (const float*)d_in[8];
  const float* evb  = (const float*)d_in[9];
  const float* argw = (const float*)d_in[10];
  const float* argb = (const float*)d_in[11];

  char* ws = (char*)d_ws;
  float* xg    = (float*)(ws + 0);           // 2*8192*1024 f32   = 64 MB
  float* wTk   = (float*)(ws + 67108864);    // 96*2048 f32       = 768 KB
  float* wS    = (float*)(ws + 67895296);    // 2048*160 f32      = 1.25 MB
  float* WcatT = (float*)(ws + 69206016);    // 512*128 f32       = 256 KB
  float* hs    = (float*)(ws + 69468160);    // 8192*512 f32      = 16 MB
  float* P     = (float*)(ws + 86245376);    // 8192*128 f32      = 4 MB
  float* trig  = (float*)(ws + 90439680);    // 8192*36 f32
  float* base  = (float*)(ws + 91619328);    // 8192*36 f32
  int*   evact = (int*)  (ws + 92798976);    // 8192 i32

  float* ev_out  = (float*)d_out;            // [64,128,34]  f32
  float* arg_out = ev_out + 278528;          // [64,128,128,36] f32

  k_pack_whh <<<2048, 256, 0, stream>>>(whhf, whhb, wTk, wS);
  k_pack_wcat<<<256, 256, 0, stream>>>(evw, argw, WcatT);
  k_xg  <<<dim3(16, 128, 2), 256, 0, stream>>>(ids, emb, wihf, wihb, bf_, bb_, xg);
  k_lstm<<<128, 1024, 0, stream>>>(xg, wTk, wS, hs);
  k_hmm <<<dim3(2, 128), 256, 0, stream>>>(hs, WcatT, P);
  k_post<<<32, 256, 0, stream>>>(P, evb, argb, ev_out, trig, base, evact);
  k_dec <<<128, 128, 0, stream>>>(trig, base, evact, argw, arg_out);
}

// Round 3
// 1438.628 us; speedup vs baseline: 3.0302x; 3.0302x over previous
//
#include <hip/hip_runtime.h>
#include <hip/hip_bf16.h>
#include <cstring>

typedef __attribute__((ext_vector_type(4))) float floatx4;
typedef unsigned int u32;
typedef unsigned short u16;

#define DEV static __device__ __forceinline__
DEV float sigf(float x){ return 1.f / (1.f + expf(-x)); }

// Sizes: B=64 L=128 E=300 H=256 4H=1024 NE=34 NA=36, M = B*L = 8192.
// ROUND 7: rounds 5/6 proved the compiler pins 1024-thr WGs at 64 VGPRs
// (VGPR_Count=64 both rounds; FETCH 4.3GB scratch traffic; LDS/occupancy and
// waves_per_eu attributes all ignored). New k_lstm needs ~30 regs: NO
// per-thread weight arrays. All W_hh streams from L2 each step in a packed
// k-major layout (wP[k/4][2048][4]: wave load = 1KB contiguous dwordx4),
// 2 batches per WG so each streamed weight feeds 2 FMAs. Grid 64 WGs
// (dir x 16... 2*32 pairs), LDS just h double-buffer + gates (~12KB).
// Model: ~2.5us/step (L2 1.9 / VALU 1.7 / LDS-broadcast 1.7, overlapped).

// ---------------------------------------------------------------------------
// k_pack_whh: w_hh f32 [2][1024][256] -> wP[(k>>2)][dir*1024+g][k&3]
__global__ __launch_bounds__(256) void k_pack_whh(const float* __restrict__ whf,
                                                  const float* __restrict__ whb,
                                                  float* __restrict__ wP)
{
  int i = blockIdx.x * 256 + threadIdx.x;            // 2*1024*256 = 524288
  if (i >= 524288) return;
  int dir = i >> 18, rem = i & 262143, g = rem >> 8, k = rem & 255;
  const float v = (dir ? whb : whf)[g*256 + k];
  wP[(size_t)(k >> 2)*8192 + (size_t)(dir*1024 + g)*4 + (k & 3)] = v;
}

// k_pack_wcat: WcatT[k][128]: col<34 event_w[col][k]; 34..69 arg_w[col-34][512+k];
//              70..105 arg_w[col-70][k]; 106..127 zero.
__global__ __launch_bounds__(256) void k_pack_wcat(const float* __restrict__ evw,
                                                   const float* __restrict__ argw,
                                                   float* __restrict__ WcatT)
{
  int i = blockIdx.x * 256 + threadIdx.x;            // 512*128 = 65536
  if (i >= 65536) return;
  int k = i >> 7, col = i & 127;
  float v = 0.f;
  if (col < 34)        v = evw[(size_t)col*512 + k];
  else if (col < 70)   v = argw[(size_t)(col-34)*1092 + 512 + k];
  else if (col < 106)  v = argw[(size_t)(col-70)*1092 + k];
  WcatT[(size_t)k*128 + col] = v;
}

// ---------------------------------------------------------------------------
// k_xg: xg[dir][m][g] = sum_e emb[ids[m]][e]*w_ih[dir][g][e] + b[dir][g]. Pure f32.
// 64x64 tile, BK=16, 256 thr, 4x4 micro.
__global__ __launch_bounds__(256) void k_xg(const int* __restrict__ ids,
    const float* __restrict__ emb,
    const float* __restrict__ wihf, const float* __restrict__ wihb,
    const float* __restrict__ bf_, const float* __restrict__ bb_,
    float* __restrict__ xg)
{
  const int dir = blockIdx.z;
  const float* W    = dir ? wihb : wihf;
  const float* bias = dir ? bb_  : bf_;
  const int n0 = blockIdx.x * 64, m0 = blockIdx.y * 64;
  __shared__ float As[16][64];
  __shared__ float Bs[16][64];
  const int tid = threadIdx.x;
  const int row = tid & 63, kk = (tid >> 6) * 4;
  const int tx = tid & 15, ty = tid >> 4;
  const size_t abase = (size_t)ids[m0 + row] * 300;
  const size_t bbase = (size_t)(n0 + row) * 300;
  float acc[4][4] = {};

  for (int k0 = 0; k0 < 300; k0 += 16) {
    __syncthreads();
    {
      const int gk = k0 + kk;
      floatx4 va = {0,0,0,0}, vb = {0,0,0,0};
      if (gk + 3 < 300) {
        va = *(const floatx4*)(emb + abase + gk);
        vb = *(const floatx4*)(W   + bbase + gk);
      } else {
        #pragma unroll
        for (int j = 0; j < 4; j++) if (gk + j < 300) {
          va[j] = emb[abase + gk + j];
          vb[j] = W[bbase + gk + j];
        }
      }
      #pragma unroll
      for (int j = 0; j < 4; j++){ As[kk+j][row] = va[j]; Bs[kk+j][row] = vb[j]; }
    }
    __syncthreads();
    #pragma unroll
    for (int k = 0; k < 16; k++){
      const floatx4 av = *(const floatx4*)&As[k][ty*4];
      const floatx4 bv = *(const floatx4*)&Bs[k][tx*4];
      #pragma unroll
      for (int i = 0; i < 4; i++)
        #pragma unroll
        for (int j = 0; j < 4; j++) acc[i][j] += av[i] * bv[j];
    }
  }
  const floatx4 bv = *(const floatx4*)(bias + n0 + tx*4);
  #pragma unroll
  for (int i = 0; i < 4; i++){
    const int m = m0 + ty*4 + i;
    floatx4 o;
    #pragma unroll
    for (int j = 0; j < 4; j++) o[j] = acc[i][j] + bv[j];
    *(floatx4*)&xg[(size_t)dir*8388608 + (size_t)m*1024 + n0 + tx*4] = o;
  }
}

// ---------------------------------------------------------------------------
// k_lstm: 64 WGs = (dir, batch-pair), 1024 thr, 1 gate/thread, 2 batches/WG.
// Zero per-thread weight state (~30 VGPRs, spill-proof at any budget).
// Weights stream from L2: wP row per 4-k = 1KB contiguous per wave load;
// each 16B of weights feeds 8 FMAs (2 batches). h via LDS b128 broadcasts.
__global__ __launch_bounds__(1024) void k_lstm(const float* __restrict__ xg,
    const float* __restrict__ wP, float* __restrict__ hs)
{
  const int wg = blockIdx.x;
  const int dir = wg >> 5, pair = wg & 31, dirbase = dir * 1024;
  const int b0 = pair * 2;
  const int t = threadIdx.x;
  __shared__ float __align__(16) hl[2][2][256];   // [step&1][batch][cell]
  __shared__ float gates[2][1024];

  const float* wp  = wP + (size_t)(dirbase + t) * 4;
  const float* xg0 = xg + (size_t)dir*8388608 + (size_t)b0*131072;

  const int bsel = t >> 8, cell = t & 255;        // valid when t < 512
  float c = 0.f;
  if (t < 512) hl[0][bsel][cell] = 0.f;
  __syncthreads();

  for (int s = 0; s < 128; s++){
    const int tstep = dir ? (127 - s) : s;
    const float x00 = __builtin_nontemporal_load(xg0 + (size_t)tstep*1024 + t);
    const float x01 = __builtin_nontemporal_load(xg0 + 131072 + (size_t)tstep*1024 + t);
    const float* h0 = hl[s & 1][0];
    const float* h1 = hl[s & 1][1];
    float a00 = 0.f, a01 = 0.f;

    #pragma unroll 4
    for (int q = 0; q < 64; q++){
      const floatx4 wv  = *(const floatx4*)(wp + (size_t)q*8192);
      const floatx4 hv0 = *(const floatx4*)&h0[q*4];
      const floatx4 hv1 = *(const floatx4*)&h1[q*4];
      #pragma unroll
      for (int e = 0; e < 4; e++){
        a00 += wv[e] * hv0[e];
        a01 += wv[e] * hv1[e];
      }
    }

    gates[0][t] = x00 + a00;
    gates[1][t] = x01 + a01;
    __syncthreads();
    if (t < 512){
      const float gi = gates[bsel][cell],       gf = gates[bsel][256 + cell],
                  gg = gates[bsel][512 + cell], go = gates[bsel][768 + cell];
      c = sigf(gf)*c + sigf(gi)*tanhf(gg);
      const float h = sigf(go)*tanhf(c);
      hl[(s + 1) & 1][bsel][cell] = h;
      hs[(size_t)(b0 + bsel)*65536 + (size_t)tstep*512 + dir*256 + cell] = h;
    }
    __syncthreads();
  }
}

// ---------------------------------------------------------------------------
// k_hmm: P[8192][128] = hs[8192][512] @ WcatT (f32, 64x64 tile, BK=16)
__global__ __launch_bounds__(256) void k_hmm(const float* __restrict__ hs,
    const float* __restrict__ WcatT, float* __restrict__ P)
{
  const int n0 = blockIdx.x * 64, m0 = blockIdx.y * 64;
  __shared__ float As[16][64];
  __shared__ float Bs[16][64];
  const int tid = threadIdx.x;
  const int row = tid & 63, kk = (tid >> 6) * 4;
  const int tx = tid & 15, ty = tid >> 4;
  float acc[4][4] = {};

  for (int k0 = 0; k0 < 512; k0 += 16) {
    __syncthreads();
    {
      const floatx4 va = *(const floatx4*)(hs + (size_t)(m0+row)*512 + k0 + kk);
      #pragma unroll
      for (int j = 0; j < 4; j++){
        As[kk+j][row] = va[j];
        Bs[kk+j][row] = WcatT[(size_t)(k0+kk+j)*128 + n0 + row];
      }
    }
    __syncthreads();
    #pragma unroll
    for (int k = 0; k < 16; k++){
      const floatx4 av = *(const floatx4*)&As[k][ty*4];
      const floatx4 bv = *(const floatx4*)&Bs[k][tx*4];
      #pragma unroll
      for (int i = 0; i < 4; i++)
        #pragma unroll
        for (int j = 0; j < 4; j++) acc[i][j] += av[i] * bv[j];
    }
  }
  #pragma unroll
  for (int i = 0; i < 4; i++){
    floatx4 o;
    #pragma unroll
    for (int j = 0; j < 4; j++) o[j] = acc[i][j];
    *(floatx4*)&P[(size_t)(m0 + ty*4 + i)*128 + n0 + tx*4] = o;
  }
}

// ---------------------------------------------------------------------------
// k_post: per row m: ev logits (+event_b) -> f32 out + argmax -> evact;
//         trig = P[34..69]; base = P[70..105] + arg_b.
__global__ __launch_bounds__(256) void k_post(const float* __restrict__ P,
    const float* __restrict__ evb, const float* __restrict__ argb,
    float* __restrict__ ev_out, float* __restrict__ trig,
    float* __restrict__ base, int* __restrict__ evact)
{
  const int m = blockIdx.x * 256 + threadIdx.x;
  const float* row = P + (size_t)m*128;
  float bestv = row[0] + evb[0]; int besti = 0;
  ev_out[(size_t)m*34] = bestv;
  for (int n = 1; n < 34; n++){
    const float v = row[n] + evb[n];
    ev_out[(size_t)m*34 + n] = v;
    if (v > bestv){ bestv = v; besti = n; }       // strict >: first-max tie rule
  }
  evact[m] = besti;
  for (int n = 0; n < 36; n++) trig[(size_t)m*36 + n] = row[34 + n];
  for (int n = 0; n < 36; n++) base[(size_t)m*36 + n] = row[70 + n] + argb[n];
}

// ---------------------------------------------------------------------------
// k_dec: 8192 independent (b,j) cells, 2 threads/cell (18 logits each).
// contrib[] updated incrementally when a g-bit flips 0->1.
__global__ __launch_bounds__(128) void k_dec(const float* __restrict__ trig,
    const float* __restrict__ base, const int* __restrict__ evact,
    const float* __restrict__ arg_w, float* __restrict__ out1)
{
  const int bb = blockIdx.x >> 1, jh = blockIdx.x & 1;
  const int tid = threadIdx.x;
  const int j = jh*64 + (tid >> 1), p = tid & 1;
  __shared__ float trig_l[128*36];
  __shared__ float Wg_l[35*36];    // [k][a], arg_w cols 1024+k
  __shared__ float Wtg_l[33*36];   // [k][a], arg_w cols 1059+k
  __shared__ int evact_l[128];

  for (int f = tid; f < 128*36; f += 128) trig_l[f] = trig[(size_t)bb*4608 + f];
  for (int f = tid; f < 35*36; f += 128){ int k = f/36, a = f - k*36; Wg_l[f]  = arg_w[(size_t)a*1092 + 1024 + k]; }
  for (int f = tid; f < 33*36; f += 128){ int k = f/36, a = f - k*36; Wtg_l[f] = arg_w[(size_t)a*1092 + 1059 + k]; }
  evact_l[tid] = evact[bb*128 + tid];

  float basev[18], contrib[18];
  #pragma unroll
  for (int x = 0; x < 18; x++){
    basev[x] = base[((size_t)bb*128 + j)*36 + p*18 + x];
    contrib[x] = 0.f;
  }
  unsigned long long garg = 0ull, gtrg = 0ull;
  __syncthreads();

  float* outb = out1 + (size_t)bb*589824 + (size_t)j*36;   // + i*4608 + p*18

  for (int i = 0; i < 128; i++){
    const float* tr = &trig_l[i*36 + p*18];
    float l[18];
    #pragma unroll
    for (int x = 0; x < 18; x++) l[x] = basev[x] + contrib[x] + tr[x];
    float mv = l[0]; int mi = p*18;
    #pragma unroll
    for (int x = 1; x < 18; x++){ if (l[x] > mv){ mv = l[x]; mi = p*18 + x; } }
    const float ov = __shfl_xor(mv, 1);
    const int   oi = __shfl_xor(mi, 1);
    const float v0 = p ? ov : mv, v1 = p ? mv : ov;
    const int   i0 = p ? oi : mi, i1 = p ? mi : oi;
    const int gidx = (v1 > v0) ? i1 : i0;          // first-max across both halves

    float* po = outb + (size_t)i*4608 + p*18;
    #pragma unroll
    for (int x = 0; x < 18; x++) po[x] = l[x];

    const int ev = evact_l[i];
    if (ev > 0 && gidx > 0){
      const int k1 = gidx - 1;
      const unsigned long long bit1 = 1ull << k1;
      if (!(garg & bit1)){
        garg |= bit1;
        const float* wc = &Wg_l[k1*36 + p*18];
        #pragma unroll
        for (int x = 0; x < 18; x++) contrib[x] += wc[x];
      }
      const int k2 = ev - 1;
      const unsigned long long bit2 = 1ull << k2;
      if (!(gtrg & bit2)){
        gtrg |= bit2;
        const float* wc = &Wtg_l[k2*36 + p*18];
        #pragma unroll
        for (int x = 0; x < 18; x++) contrib[x] += wc[x];
      }
    }
  }
}

// ---------------------------------------------------------------------------
extern "C" void kernel_launch(void* const* d_in, const int* in_sizes, int n_in,
                              void* d_out, int out_size, void* d_ws, size_t ws_size,
                              hipStream_t stream)
{
  const int*   ids  = (const int*)d_in[0];
  const float* emb  = (const float*)d_in[1];
  const float* wihf = (const float*)d_in[2];
  const float* whhf = (const float*)d_in[3];
  const float* bf_  = (const float*)d_in[4];
  const float* wihb = (const float*)d_in[5];
  const float* whhb = (const float*)d_in[6];
  const float* bb_  = (const float*)d_in[7];
  const float* evw  = (const float*)d_in[8];
  const float* evb  = (const float*)d_in[9];
  const float* argw = (const float*)d_in[10];
  const float* argb = (const float*)d_in[11];

  char* ws = (char*)d_ws;
  float* xg    = (float*)(ws + 0);           // 2*8192*1024 f32   = 64 MB
  float* wP    = (float*)(ws + 67108864);    // 64*2048*4 f32     = 2 MB
  float* WcatT = (float*)(ws + 69206016);    // 512*128 f32       = 256 KB
  float* hs    = (float*)(ws + 69468160);    // 8192*512 f32      = 16 MB
  float* P     = (float*)(ws + 86245376);    // 8192*128 f32      = 4 MB
  float* trig  = (float*)(ws + 90439680);    // 8192*36 f32
  float* base  = (float*)(ws + 91619328);    // 8192*36 f32
  int*   evact = (int*)  (ws + 92798976);    // 8192 i32

  float* ev_out  = (float*)d_out;            // [64,128,34]  f32
  float* arg_out = ev_out + 278528;          // [64,128,128,36] f32

  k_pack_whh <<<2048, 256, 0, stream>>>(whhf, whhb, wP);
  k_pack_wcat<<<256, 256, 0, stream>>>(evw, argw, WcatT);
  k_xg  <<<dim3(16, 128, 2), 256, 0, stream>>>(ids, emb, wihf, wihb, bf_, bb_, xg);
  k_lstm<<<64, 1024, 0, stream>>>(xg, wP, hs);
  k_hmm <<<dim3(2, 128), 256, 0, stream>>>(hs, WcatT, P);
  k_post<<<32, 256, 0, stream>>>(P, evb, argb, ev_out, trig, base, evact);
  k_dec <<<128, 128, 0, stream>>>(trig, base, evact, argw, arg_out);
}

// Round 4
// 1409.264 us; speedup vs baseline: 3.0934x; 1.0208x over previous
//
#include <hip/hip_runtime.h>
#include <hip/hip_bf16.h>
#include <cstring>

typedef __attribute__((ext_vector_type(4))) float floatx4;
typedef unsigned int u32;
typedef unsigned short u16;

#define DEV static __device__ __forceinline__
DEV float sigf(float x){ return 1.f / (1.f + expf(-x)); }

// Sizes: B=64 L=128 E=300 H=256 4H=1024 NE=34 NA=36, M = B*L = 8192.
// ROUND 8: round 7 (64 WGs, 2 batches/WG) hit the LDS-return-bus wall:
// 2048 broadcast ds_read_b128 per CU per step x ~10cyc = 8.3us/step == measured
// 1065us/128. Broadcasts still fill 64 lanes x 16B on the return bus, so the
// 4B/MAC LDS tax is structural; the remaining lever is CU count.
// Fix: 128 WGs x 1 batch (1 (dir,b) per WG): per-WG LDS reads halve, active
// CUs double. New floors/step: LDS ~3.4us, L2 weight stream 16MB/XCD ~3.5us
// -> ~450-500us. Unroll 8 covers L2 latency (VGPR ~50 < 64 budget, no spill).

// ---------------------------------------------------------------------------
// k_pack_whh: w_hh f32 [2][1024][256] -> wP[(k>>2)][dir*1024+g][k&3]
__global__ __launch_bounds__(256) void k_pack_whh(const float* __restrict__ whf,
                                                  const float* __restrict__ whb,
                                                  float* __restrict__ wP)
{
  int i = blockIdx.x * 256 + threadIdx.x;            // 2*1024*256 = 524288
  if (i >= 524288) return;
  int dir = i >> 18, rem = i & 262143, g = rem >> 8, k = rem & 255;
  const float v = (dir ? whb : whf)[g*256 + k];
  wP[(size_t)(k >> 2)*8192 + (size_t)(dir*1024 + g)*4 + (k & 3)] = v;
}

// k_pack_wcat: WcatT[k][128]: col<34 event_w[col][k]; 34..69 arg_w[col-34][512+k];
//              70..105 arg_w[col-70][k]; 106..127 zero.
__global__ __launch_bounds__(256) void k_pack_wcat(const float* __restrict__ evw,
                                                   const float* __restrict__ argw,
                                                   float* __restrict__ WcatT)
{
  int i = blockIdx.x * 256 + threadIdx.x;            // 512*128 = 65536
  if (i >= 65536) return;
  int k = i >> 7, col = i & 127;
  float v = 0.f;
  if (col < 34)        v = evw[(size_t)col*512 + k];
  else if (col < 70)   v = argw[(size_t)(col-34)*1092 + 512 + k];
  else if (col < 106)  v = argw[(size_t)(col-70)*1092 + k];
  WcatT[(size_t)k*128 + col] = v;
}

// ---------------------------------------------------------------------------
// k_xg: xg[dir][m][g] = sum_e emb[ids[m]][e]*w_ih[dir][g][e] + b[dir][g]. Pure f32.
// 64x64 tile, BK=16, 256 thr, 4x4 micro.
__global__ __launch_bounds__(256) void k_xg(const int* __restrict__ ids,
    const float* __restrict__ emb,
    const float* __restrict__ wihf, const float* __restrict__ wihb,
    const float* __restrict__ bf_, const float* __restrict__ bb_,
    float* __restrict__ xg)
{
  const int dir = blockIdx.z;
  const float* W    = dir ? wihb : wihf;
  const float* bias = dir ? bb_  : bf_;
  const int n0 = blockIdx.x * 64, m0 = blockIdx.y * 64;
  __shared__ float As[16][64];
  __shared__ float Bs[16][64];
  const int tid = threadIdx.x;
  const int row = tid & 63, kk = (tid >> 6) * 4;
  const int tx = tid & 15, ty = tid >> 4;
  const size_t abase = (size_t)ids[m0 + row] * 300;
  const size_t bbase = (size_t)(n0 + row) * 300;
  float acc[4][4] = {};

  for (int k0 = 0; k0 < 300; k0 += 16) {
    __syncthreads();
    {
      const int gk = k0 + kk;
      floatx4 va = {0,0,0,0}, vb = {0,0,0,0};
      if (gk + 3 < 300) {
        va = *(const floatx4*)(emb + abase + gk);
        vb = *(const floatx4*)(W   + bbase + gk);
      } else {
        #pragma unroll
        for (int j = 0; j < 4; j++) if (gk + j < 300) {
          va[j] = emb[abase + gk + j];
          vb[j] = W[bbase + gk + j];
        }
      }
      #pragma unroll
      for (int j = 0; j < 4; j++){ As[kk+j][row] = va[j]; Bs[kk+j][row] = vb[j]; }
    }
    __syncthreads();
    #pragma unroll
    for (int k = 0; k < 16; k++){
      const floatx4 av = *(const floatx4*)&As[k][ty*4];
      const floatx4 bv = *(const floatx4*)&Bs[k][tx*4];
      #pragma unroll
      for (int i = 0; i < 4; i++)
        #pragma unroll
        for (int j = 0; j < 4; j++) acc[i][j] += av[i] * bv[j];
    }
  }
  const floatx4 bv = *(const floatx4*)(bias + n0 + tx*4);
  #pragma unroll
  for (int i = 0; i < 4; i++){
    const int m = m0 + ty*4 + i;
    floatx4 o;
    #pragma unroll
    for (int j = 0; j < 4; j++) o[j] = acc[i][j] + bv[j];
    *(floatx4*)&xg[(size_t)dir*8388608 + (size_t)m*1024 + n0 + tx*4] = o;
  }
}

// ---------------------------------------------------------------------------
// k_lstm: 128 WGs = (dir, b), 1024 thr, 1 gate/thread, 1 batch/WG.
// Zero per-thread weight state (~50 VGPRs incl. unroll-8 load buffers).
// Weights stream from L2 (wP row per 4-k = 1KB contiguous per wave load);
// h via LDS b128 broadcasts (1 per iter -> half of round 7's per-WG LDS).
__global__ __launch_bounds__(1024) void k_lstm(const float* __restrict__ xg,
    const float* __restrict__ wP, float* __restrict__ hs)
{
  const int wg = blockIdx.x;
  const int dir = wg >> 6, b = wg & 63, dirbase = dir * 1024;
  const int t = threadIdx.x;
  __shared__ float __align__(16) hl[2][256];
  __shared__ float gates[1024];

  const float* wp  = wP + (size_t)(dirbase + t) * 4;
  const float* xg0 = xg + (size_t)dir*8388608 + (size_t)b*131072;

  float c = 0.f;
  if (t < 256) hl[0][t] = 0.f;
  __syncthreads();

  for (int s = 0; s < 128; s++){
    const int tstep = dir ? (127 - s) : s;
    const float x0 = __builtin_nontemporal_load(xg0 + (size_t)tstep*1024 + t);
    const float* h0 = hl[s & 1];
    float a0 = 0.f;

    #pragma unroll 8
    for (int q = 0; q < 64; q++){
      const floatx4 wv = *(const floatx4*)(wp + (size_t)q*8192);
      const floatx4 hv = *(const floatx4*)&h0[q*4];
      #pragma unroll
      for (int e = 0; e < 4; e++) a0 += wv[e] * hv[e];
    }

    gates[t] = x0 + a0;
    __syncthreads();
    if (t < 256){
      const float gi = gates[t],       gf = gates[256 + t],
                  gg = gates[512 + t], go = gates[768 + t];
      c = sigf(gf)*c + sigf(gi)*tanhf(gg);
      const float h = sigf(go)*tanhf(c);
      hl[(s + 1) & 1][t] = h;
      hs[(size_t)b*65536 + (size_t)tstep*512 + dir*256 + t] = h;
    }
    __syncthreads();
  }
}

// ---------------------------------------------------------------------------
// k_hmm: P[8192][128] = hs[8192][512] @ WcatT (f32, 64x64 tile, BK=16)
__global__ __launch_bounds__(256) void k_hmm(const float* __restrict__ hs,
    const float* __restrict__ WcatT, float* __restrict__ P)
{
  const int n0 = blockIdx.x * 64, m0 = blockIdx.y * 64;
  __shared__ float As[16][64];
  __shared__ float Bs[16][64];
  const int tid = threadIdx.x;
  const int row = tid & 63, kk = (tid >> 6) * 4;
  const int tx = tid & 15, ty = tid >> 4;
  float acc[4][4] = {};

  for (int k0 = 0; k0 < 512; k0 += 16) {
    __syncthreads();
    {
      const floatx4 va = *(const floatx4*)(hs + (size_t)(m0+row)*512 + k0 + kk);
      #pragma unroll
      for (int j = 0; j < 4; j++){
        As[kk+j][row] = va[j];
        Bs[kk+j][row] = WcatT[(size_t)(k0+kk+j)*128 + n0 + row];
      }
    }
    __syncthreads();
    #pragma unroll
    for (int k = 0; k < 16; k++){
      const floatx4 av = *(const floatx4*)&As[k][ty*4];
      const floatx4 bv = *(const floatx4*)&Bs[k][tx*4];
      #pragma unroll
      for (int i = 0; i < 4; i++)
        #pragma unroll
        for (int j = 0; j < 4; j++) acc[i][j] += av[i] * bv[j];
    }
  }
  #pragma unroll
  for (int i = 0; i < 4; i++){
    floatx4 o;
    #pragma unroll
    for (int j = 0; j < 4; j++) o[j] = acc[i][j];
    *(floatx4*)&P[(size_t)(m0 + ty*4 + i)*128 + n0 + tx*4] = o;
  }
}

// ---------------------------------------------------------------------------
// k_post: per row m: ev logits (+event_b) -> f32 out + argmax -> evact;
//         trig = P[34..69]; base = P[70..105] + arg_b.
__global__ __launch_bounds__(256) void k_post(const float* __restrict__ P,
    const float* __restrict__ evb, const float* __restrict__ argb,
    float* __restrict__ ev_out, float* __restrict__ trig,
    float* __restrict__ base, int* __restrict__ evact)
{
  const int m = blockIdx.x * 256 + threadIdx.x;
  const float* row = P + (size_t)m*128;
  float bestv = row[0] + evb[0]; int besti = 0;
  ev_out[(size_t)m*34] = bestv;
  for (int n = 1; n < 34; n++){
    const float v = row[n] + evb[n];
    ev_out[(size_t)m*34 + n] = v;
    if (v > bestv){ bestv = v; besti = n; }       // strict >: first-max tie rule
  }
  evact[m] = besti;
  for (int n = 0; n < 36; n++) trig[(size_t)m*36 + n] = row[34 + n];
  for (int n = 0; n < 36; n++) base[(size_t)m*36 + n] = row[70 + n] + argb[n];
}

// ---------------------------------------------------------------------------
// k_dec: 8192 independent (b,j) cells, 2 threads/cell (18 logits each).
// contrib[] updated incrementally when a g-bit flips 0->1.
__global__ __launch_bounds__(128) void k_dec(const float* __restrict__ trig,
    const float* __restrict__ base, const int* __restrict__ evact,
    const float* __restrict__ arg_w, float* __restrict__ out1)
{
  const int bb = blockIdx.x >> 1, jh = blockIdx.x & 1;
  const int tid = threadIdx.x;
  const int j = jh*64 + (tid >> 1), p = tid & 1;
  __shared__ float trig_l[128*36];
  __shared__ float Wg_l[35*36];    // [k][a], arg_w cols 1024+k
  __shared__ float Wtg_l[33*36];   // [k][a], arg_w cols 1059+k
  __shared__ int evact_l[128];

  for (int f = tid; f < 128*36; f += 128) trig_l[f] = trig[(size_t)bb*4608 + f];
  for (int f = tid; f < 35*36; f += 128){ int k = f/36, a = f - k*36; Wg_l[f]  = arg_w[(size_t)a*1092 + 1024 + k]; }
  for (int f = tid; f < 33*36; f += 128){ int k = f/36, a = f - k*36; Wtg_l[f] = arg_w[(size_t)a*1092 + 1059 + k]; }
  evact_l[tid] = evact[bb*128 + tid];

  float basev[18], contrib[18];
  #pragma unroll
  for (int x = 0; x < 18; x++){
    basev[x] = base[((size_t)bb*128 + j)*36 + p*18 + x];
    contrib[x] = 0.f;
  }
  unsigned long long garg = 0ull, gtrg = 0ull;
  __syncthreads();

  float* outb = out1 + (size_t)bb*589824 + (size_t)j*36;   // + i*4608 + p*18

  for (int i = 0; i < 128; i++){
    const float* tr = &trig_l[i*36 + p*18];
    float l[18];
    #pragma unroll
    for (int x = 0; x < 18; x++) l[x] = basev[x] + contrib[x] + tr[x];
    float mv = l[0]; int mi = p*18;
    #pragma unroll
    for (int x = 1; x < 18; x++){ if (l[x] > mv){ mv = l[x]; mi = p*18 + x; } }
    const float ov = __shfl_xor(mv, 1);
    const int   oi = __shfl_xor(mi, 1);
    const float v0 = p ? ov : mv, v1 = p ? mv : ov;
    const int   i0 = p ? oi : mi, i1 = p ? mi : oi;
    const int gidx = (v1 > v0) ? i1 : i0;          // first-max across both halves

    float* po = outb + (size_t)i*4608 + p*18;
    #pragma unroll
    for (int x = 0; x < 18; x++) po[x] = l[x];

    const int ev = evact_l[i];
    if (ev > 0 && gidx > 0){
      const int k1 = gidx - 1;
      const unsigned long long bit1 = 1ull << k1;
      if (!(garg & bit1)){
        garg |= bit1;
        const float* wc = &Wg_l[k1*36 + p*18];
        #pragma unroll
        for (int x = 0; x < 18; x++) contrib[x] += wc[x];
      }
      const int k2 = ev - 1;
      const unsigned long long bit2 = 1ull << k2;
      if (!(gtrg & bit2)){
        gtrg |= bit2;
        const float* wc = &Wtg_l[k2*36 + p*18];
        #pragma unroll
        for (int x = 0; x < 18; x++) contrib[x] += wc[x];
      }
    }
  }
}

// ---------------------------------------------------------------------------
extern "C" void kernel_launch(void* const* d_in, const int* in_sizes, int n_in,
                              void* d_out, int out_size, void* d_ws, size_t ws_size,
                              hipStream_t stream)
{
  const int*   ids  = (const int*)d_in[0];
  const float* emb  = (const float*)d_in[1];
  const float* wihf = (const float*)d_in[2];
  const float* whhf = (const float*)d_in[3];
  const float* bf_  = (const float*)d_in[4];
  const float* wihb = (const float*)d_in[5];
  const float* whhb = (const float*)d_in[6];
  const float* bb_  = (const float*)d_in[7];
  const float* evw  = (const float*)d_in[8];
  const float* evb  = (const float*)d_in[9];
  const float* argw = (const float*)d_in[10];
  const float* argb = (const float*)d_in[11];

  char* ws = (char*)d_ws;
  float* xg    = (float*)(ws + 0);           // 2*8192*1024 f32   = 64 MB
  float* wP    = (float*)(ws + 67108864);    // 64*2048*4 f32     = 2 MB
  float* WcatT = (float*)(ws + 69206016);    // 512*128 f32       = 256 KB
  float* hs    = (float*)(ws + 69468160);    // 8192*512 f32      = 16 MB
  float* P     = (float*)(ws + 86245376);    // 8192*128 f32      = 4 MB
  float* trig  = (float*)(ws + 90439680);    // 8192*36 f32
  float* base  = (float*)(ws + 91619328);    // 8192*36 f32
  int*   evact = (int*)  (ws + 92798976);    // 8192 i32

  float* ev_out  = (float*)d_out;            // [64,128,34]  f32
  float* arg_out = ev_out + 278528;          // [64,128,128,36] f32

  k_pack_whh <<<2048, 256, 0, stream>>>(whhf, whhb, wP);
  k_pack_wcat<<<256, 256, 0, stream>>>(evw, argw, WcatT);
  k_xg  <<<dim3(16, 128, 2), 256, 0, stream>>>(ids, emb, wihf, wihb, bf_, bb_, xg);
  k_lstm<<<128, 1024, 0, stream>>>(xg, wP, hs);
  k_hmm <<<dim3(2, 128), 256, 0, stream>>>(hs, WcatT, P);
  k_post<<<32, 256, 0, stream>>>(P, evb, argb, ev_out, trig, base, evact);
  k_dec <<<128, 128, 0, stream>>>(trig, base, evact, argw, arg_out);
}